// Round 9
// baseline (139.060 us; speedup 1.0000x reference)
//
#include <hip/hip_runtime.h>

#define HH 448
#define WW 608
#define CC 64
#define S1 32
#define S2 16
#define HW (HH * WW)
#define BLK 1024                    // 16 waves: 9.5 compute + helpers; 8192 = 8*BLK exactly
#define W2F4 (S1 * CC * S2 / 4)     // 8192 float4 = 128 KB
#define NSTG 8                      // float4 per thread, no tail

// LDS layout: word(k, c, k2) = c*512 + (k2>>1)*64 + ((2k + 4*(c&15)) & 63) + (k2&1)
// READ (critical, 512 ds_read_b64/thread): lanes vary k1 -> bank = (2k1+4(c&15))%32,
//   distinct for k1 mod 16 -> <=2-way = throughput-free (m136). The ~5.5M
//   SQ_LDS_BANK_CONFLICT this produces is a 2-way counting artifact, NOT a cost
//   (round-8 post-mortem: 4480 waves x ~1240 cyc matches counter exactly).
// WRITE: 16 b64/thread, 8-way (2.94x on ~100 cyc/wave). Negligible volume.
// GLOBAL staging reads: consecutive-lane-consecutive-float4, fully coalesced
//   (round 7 proved swizzled-source global_load_lds destroys this: 780 GB/s).
//
// BLK=1024 rationale (round 8 -> 9): occupancy 24.5% with 10 waves/CU was the
// binding constraint (VALUBusy 20.7, latency-bound). 16 waves/CU during the
// staging+stage-1 phase hides xv/staging latency; threads 608..1023 only stage.
// VGPR must be <=128 for 16-wave residency (m69 steps: 64/128/256).
//
// NUMERICS (do not change): stage-1 per class = bias first then channels 0..63
// ascending, ONE sequential chain; stage-2 = bias init then c ascending, j8
// ascending; argmax strict '>' ascending. All register arrays fully unrolled.
// Round 3 proved re-association flips near-tie argmaxes past threshold.

__launch_bounds__(BLK)
__global__ void reg2stage_kernel(const float* __restrict__ x,
                                 const float* __restrict__ w1,
                                 const float* __restrict__ b1,
                                 const float* __restrict__ w2,
                                 const float* __restrict__ b2,
                                 const float* __restrict__ w3,
                                 const float* __restrict__ b3,
                                 float* __restrict__ out) {
    __shared__ float w2s[S1 * CC * S2];   // 128 KB -> 1 block/CU

    const int h = blockIdx.x;
    const int tid = threadIdx.x;
    const bool active = (tid < WW);
    const int w = tid;

    const float* __restrict__ xp = x + (size_t)h * WW + w;
    const float4* __restrict__ w2row4 =
        reinterpret_cast<const float4*>(w2 + (size_t)h * (S1 * CC * S2));

    // ---- 1) xv loads (oldest in vmcnt queue) ----
    float xv[CC];
    if (active) {
#pragma unroll
        for (int c = 0; c < CC; ++c) xv[c] = xp[(size_t)c * HW];
    }

    // ---- 2) staging loads: 8 perfectly-coalesced float4 per thread ----
    float4 stg[NSTG];
#pragma unroll
    for (int i = 0; i < NSTG; ++i) stg[i] = w2row4[tid + i * BLK];

    // ---- 3) stage 1: per-row GEMV + argmax (staging loads in flight) ----
    int k1 = 0;
    if (active) {
        const float* __restrict__ w1r = w1 + (size_t)h * (S1 * CC);
        const float* __restrict__ b1r = b1 + (size_t)h * S1;
        float best1 = -INFINITY;
        for (int k = 0; k < S1; ++k) {
            float acc = b1r[k];
            const float* __restrict__ wk = w1r + k * CC;
#pragma unroll
            for (int c = 0; c < CC; ++c) acc += xv[c] * wk[c];
            if (acc > best1) { best1 = acc; k1 = k; }
        }
    }

    // ---- 4) write staged w2 to LDS (swizzled word layout) ----
#pragma unroll
    for (int i = 0; i < NSTG; ++i) {
        const int e4 = tid + i * BLK;
        const int k = e4 >> 8;                // class
        const int c = (e4 >> 2) & 63;         // channel
        const int q = e4 & 3;                 // k2 quad
        const int s = (2 * k + 4 * (c & 15)) & 63;
        float* __restrict__ base = &w2s[c * 512 + s];
        *reinterpret_cast<float2*>(base + (2 * q) * 64) =
            make_float2(stg[i].x, stg[i].y);
        *reinterpret_cast<float2*>(base + (2 * q + 1) * 64) =
            make_float2(stg[i].z, stg[i].w);
    }
    __syncthreads();
    if (!active) return;                       // helpers (608..1023) exit

    // ---- 5) stage 2: (C x S2) matvec, ds_read_b64, <=2-way banks ----
    float acc2[S2];
    {
        const float* __restrict__ b2k = b2 + ((size_t)h * S1 + k1) * S2;
#pragma unroll
        for (int q = 0; q < 4; ++q) {
            const float4 bq = reinterpret_cast<const float4*>(b2k)[q];
            acc2[4 * q + 0] = bq.x;
            acc2[4 * q + 1] = bq.y;
            acc2[4 * q + 2] = bq.z;
            acc2[4 * q + 3] = bq.w;
        }
    }
    const int k1x2 = 2 * k1;
#pragma unroll
    for (int c = 0; c < CC; ++c) {
        const float xc = xv[c];
        const int sw = (k1x2 + 4 * (c & 15)) & 63;
        const float2* __restrict__ p =
            reinterpret_cast<const float2*>(&w2s[c * 512 + sw]);
#pragma unroll
        for (int j8 = 0; j8 < 8; ++j8) {      // k2 pair (2j8, 2j8+1)
            const float2 v = p[j8 * 32];      // +256 B imm offset per j8
            acc2[2 * j8 + 0] += xc * v.x;
            acc2[2 * j8 + 1] += xc * v.y;
        }
    }

    float best2 = -INFINITY;
    int k2b = 0;
#pragma unroll
    for (int k2 = 0; k2 < S2; ++k2) {
        if (acc2[k2] > best2) { best2 = acc2[k2]; k2b = k2; }
    }

    // ---- 6) stage 3: (C x 2) matvec gathered from global (L2/L3 resident) ----
    const size_t ind2 = ((size_t)h * S1 + k1) * S2 + k2b;
    const float4* __restrict__ w3p =
        reinterpret_cast<const float4*>(w3 + ind2 * (CC * 2));
    float r0 = b3[ind2 * 2];
    float r1 = b3[ind2 * 2 + 1];
#pragma unroll
    for (int j = 0; j < 32; ++j) {            // channel pair (2j, 2j+1)
        const float4 q = w3p[j];
        r0 += xv[2 * j] * q.x + xv[2 * j + 1] * q.z;
        r1 += xv[2 * j] * q.y + xv[2 * j + 1] * q.w;
    }

    const int loc = k1 * S2 + k2b;            // inds2 - h*S1*S2
    const float x_out = ((float)loc + r0) * 0.5f;
    const float mask = (r1 >= 0.0f) ? r1 : 0.01f * r1;

    out[(size_t)h * WW + w] = x_out;
    out[(size_t)HW + (size_t)h * WW + w] = mask;
}

extern "C" void kernel_launch(void* const* d_in, const int* in_sizes, int n_in,
                              void* d_out, int out_size, void* d_ws, size_t ws_size,
                              hipStream_t stream) {
    const float* x  = (const float*)d_in[0];
    const float* w1 = (const float*)d_in[1];
    const float* b1 = (const float*)d_in[2];
    const float* w2 = (const float*)d_in[3];
    const float* b2 = (const float*)d_in[4];
    const float* w3 = (const float*)d_in[5];
    const float* b3 = (const float*)d_in[6];
    float* out = (float*)d_out;

    reg2stage_kernel<<<dim3(HH), dim3(BLK), 0, stream>>>(x, w1, b1, w2, b2, w3, b3, out);
}

// Round 10
// 111.560 us; speedup vs baseline: 1.2465x; 1.2465x over previous
//
#include <hip/hip_runtime.h>

#define HH 448
#define WW 608
#define CC 64
#define S1 32
#define S2 16
#define HW (HH * WW)
#define BLK 640
#define HF4 4096     // float4 per 32-channel half (32 k * 32 cl * 4 q)
#define NFULL 6      // 640*6 = 3840
#define TAIL 256     // 4096 - 3840

// Per-half LDS layout (16384 words = 64 KB):
//   word(k, cl, k2) = cl*512 + (k2>>1)*64 + ((2k + 4*(cl&15)) & 63) + (k2&1)
// READ (critical path): per (cl, j8) instr lanes vary k1 -> bank=(2k1+4(cl&15))%32,
//   distinct for k1 mod 16 -> <=2-way = throughput-free (m136; round-8 confirmed the
//   ~5.5M SQ_LDS_BANK_CONFLICT is a 2-way counting artifact, not a cost).
// WRITE: 14 b64/thread, ~4-way, negligible volume.
// GLOBAL staging: consecutive-lane-consecutive-float4 (fully coalesced; round 7
//   proved swizzled-source global_load_lds destroys this).
// STRUCTURE: 64 KB halves -> 2 blocks/CU co-resident (round 2's 84.5us magic —
//   inter-block overlap is the only latency hiding the allocator can't undo).
//   Half-1 global loads issued before phase-A barrier -> in flight under phase-A.
// (640,3): the only launch_bounds that historically gives <=102 VGPR w/o spill
//   ((640,5) -> 48+full spill; plain 640 w/ BLK=1024 -> 64+reload).
//
// NUMERICS (do not change): stage-1 per class = bias first then channels 0..63
// ascending, ONE sequential chain; stage-2 = bias init then c ascending (phase A
// c=0..31, phase B c=32..63), j8 ascending within c; argmax strict '>' ascending.
// All register arrays fully unrolled. Round 3: re-association flips argmaxes.

__launch_bounds__(BLK, 3)
__global__ void reg2stage_kernel(const float* __restrict__ x,
                                 const float* __restrict__ w1,
                                 const float* __restrict__ b1,
                                 const float* __restrict__ w2,
                                 const float* __restrict__ b2,
                                 const float* __restrict__ w3,
                                 const float* __restrict__ b3,
                                 float* __restrict__ out) {
    __shared__ float w2s[16384];   // 64 KB (one 32-channel half)

    const int h = blockIdx.x;
    const int tid = threadIdx.x;
    const bool active = (tid < WW);
    const int w = tid;

    const float* __restrict__ xp = x + (size_t)h * WW + w;
    const float4* __restrict__ w2row4 =
        reinterpret_cast<const float4*>(w2 + (size_t)h * (S1 * CC * S2));

    // ---- 1) xv loads (needed first, by stage 1) ----
    float xv[CC];
    if (active) {
#pragma unroll
        for (int c = 0; c < CC; ++c) xv[c] = xp[(size_t)c * HW];
    }

    // ---- 2) issue half-0 staging loads (coalesced; e4=k*128+cl*4+q) ----
    //      global f4 idx = e4 + (e4>>7)*128 + hf*128
    float4 stg[NFULL + 1];
#pragma unroll
    for (int i = 0; i < NFULL; ++i) {
        const int e4 = tid + i * BLK;
        stg[i] = w2row4[e4 + ((e4 >> 7) << 7)];
    }
    if (tid < TAIL) {
        const int e4 = NFULL * BLK + tid;
        stg[NFULL] = w2row4[e4 + ((e4 >> 7) << 7)];
    }

    // ---- 3) stage 1: per-row GEMV + argmax (staging in flight) ----
    int k1 = 0;
    if (active) {
        const float* __restrict__ w1r = w1 + (size_t)h * (S1 * CC);
        const float* __restrict__ b1r = b1 + (size_t)h * S1;
        float best1 = -INFINITY;
        for (int k = 0; k < S1; ++k) {
            float acc = b1r[k];
            const float* __restrict__ wk = w1r + k * CC;
#pragma unroll
            for (int c = 0; c < CC; ++c) acc += xv[c] * wk[c];
            if (acc > best1) { best1 = acc; k1 = k; }
        }
    }

    // ---- 4) write half-0 to LDS ----
#pragma unroll
    for (int i = 0; i < NFULL + 1; ++i) {
        const int e4 = tid + i * BLK;
        if (i < NFULL || tid < TAIL) {
            const int k = e4 >> 7;
            const int r = e4 & 127;
            const int cl = r >> 2;
            const int q = r & 3;
            float* __restrict__ base =
                &w2s[cl * 512 + ((2 * k + 4 * (cl & 15)) & 63)];
            *reinterpret_cast<float2*>(base + (2 * q) * 64) =
                make_float2(stg[i].x, stg[i].y);
            *reinterpret_cast<float2*>(base + (2 * q + 1) * 64) =
                make_float2(stg[i].z, stg[i].w);
        }
    }

    // ---- 5) issue half-1 staging loads (fly under phase-A compute) ----
#pragma unroll
    for (int i = 0; i < NFULL; ++i) {
        const int e4 = tid + i * BLK;
        stg[i] = w2row4[e4 + ((e4 >> 7) << 7) + 128];
    }
    if (tid < TAIL) {
        const int e4 = NFULL * BLK + tid;
        stg[NFULL] = w2row4[e4 + ((e4 >> 7) << 7) + 128];
    }

    __syncthreads();   // half-0 visible

    // ---- 6) stage 2 phase A: channels 0..31 ----
    float acc2[S2];
    const int k1x2 = 2 * k1;
    if (active) {
        const float* __restrict__ b2k = b2 + ((size_t)h * S1 + k1) * S2;
#pragma unroll
        for (int q = 0; q < 4; ++q) {
            const float4 bq = reinterpret_cast<const float4*>(b2k)[q];
            acc2[4 * q + 0] = bq.x;
            acc2[4 * q + 1] = bq.y;
            acc2[4 * q + 2] = bq.z;
            acc2[4 * q + 3] = bq.w;
        }
#pragma unroll
        for (int cl = 0; cl < 32; ++cl) {
            const float xc = xv[cl];
            const float2* __restrict__ p = reinterpret_cast<const float2*>(
                &w2s[cl * 512 + ((k1x2 + 4 * (cl & 15)) & 63)]);
#pragma unroll
            for (int j8 = 0; j8 < 8; ++j8) {
                const float2 v = p[j8 * 32];
                acc2[2 * j8 + 0] += xc * v.x;
                acc2[2 * j8 + 1] += xc * v.y;
            }
        }
    }
    __syncthreads();   // phase-A reads done

    // ---- 7) write half-1 to LDS ----
#pragma unroll
    for (int i = 0; i < NFULL + 1; ++i) {
        const int e4 = tid + i * BLK;
        if (i < NFULL || tid < TAIL) {
            const int k = e4 >> 7;
            const int r = e4 & 127;
            const int cl = r >> 2;
            const int q = r & 3;
            float* __restrict__ base =
                &w2s[cl * 512 + ((2 * k + 4 * (cl & 15)) & 63)];
            *reinterpret_cast<float2*>(base + (2 * q) * 64) =
                make_float2(stg[i].x, stg[i].y);
            *reinterpret_cast<float2*>(base + (2 * q + 1) * 64) =
                make_float2(stg[i].z, stg[i].w);
        }
    }
    __syncthreads();   // half-1 visible
    if (!active) return;

    // ---- 8) stage 2 phase B: channels 32..63 ----
#pragma unroll
    for (int cl = 0; cl < 32; ++cl) {
        const float xc = xv[32 + cl];
        const float2* __restrict__ p = reinterpret_cast<const float2*>(
            &w2s[cl * 512 + ((k1x2 + 4 * (cl & 15)) & 63)]);
#pragma unroll
        for (int j8 = 0; j8 < 8; ++j8) {
            const float2 v = p[j8 * 32];
            acc2[2 * j8 + 0] += xc * v.x;
            acc2[2 * j8 + 1] += xc * v.y;
        }
    }

    float best2 = -INFINITY;
    int k2b = 0;
#pragma unroll
    for (int k2 = 0; k2 < S2; ++k2) {
        if (acc2[k2] > best2) { best2 = acc2[k2]; k2b = k2; }
    }

    // ---- 9) stage 3: (C x 2) matvec gathered from global (L2/L3 resident) ----
    const size_t ind2 = ((size_t)h * S1 + k1) * S2 + k2b;
    const float4* __restrict__ w3p =
        reinterpret_cast<const float4*>(w3 + ind2 * (CC * 2));
    float r0 = b3[ind2 * 2];
    float r1 = b3[ind2 * 2 + 1];
#pragma unroll
    for (int j = 0; j < 32; ++j) {
        const float4 q = w3p[j];
        r0 += xv[2 * j] * q.x + xv[2 * j + 1] * q.z;
        r1 += xv[2 * j] * q.y + xv[2 * j + 1] * q.w;
    }

    const int loc = k1 * S2 + k2b;
    const float x_out = ((float)loc + r0) * 0.5f;
    const float mask = (r1 >= 0.0f) ? r1 : 0.01f * r1;

    out[(size_t)h * WW + w] = x_out;
    out[(size_t)HW + (size_t)h * WW + w] = mask;
}

extern "C" void kernel_launch(void* const* d_in, const int* in_sizes, int n_in,
                              void* d_out, int out_size, void* d_ws, size_t ws_size,
                              hipStream_t stream) {
    const float* x  = (const float*)d_in[0];
    const float* w1 = (const float*)d_in[1];
    const float* b1 = (const float*)d_in[2];
    const float* w2 = (const float*)d_in[3];
    const float* b2 = (const float*)d_in[4];
    const float* w3 = (const float*)d_in[5];
    const float* b3 = (const float*)d_in[6];
    float* out = (float*)d_out;

    reg2stage_kernel<<<dim3(HH), dim3(BLK), 0, stream>>>(x, w1, b1, w2, b2, w3, b3, out);
}